// Round 4
// baseline (85.236 us; speedup 1.0000x reference)
//
#include <hip/hip_runtime.h>

// EmbeddingBagCollection: 4 tables, W[1M,64] fp32, mean-pool over jagged bags.
// block = 8 bags, wave = table, lane = 16*g + s (g=row group, s=float4 slot).
// Continuous chunk pipeline per wave: while chunk i's 16 branch-free float4
// gathers (16 KB) are in flight, chunk i+1's index load is also outstanding.
// Bags are visited in order (empty bags as zero-length chunks -> store zeros),
// so one accumulator set suffices; bag-close = shfl_xor reduce + store.

#define NBAGS 8192
#define DIM 64
#define NB 8                    // bags per block
#define OFF(i) __shfl(off_reg, (i))

__global__ __launch_bounds__(256) void ebc_kernel(
    const float* __restrict__ W0, const int* __restrict__ v0, const int* __restrict__ o0,
    const float* __restrict__ W1, const int* __restrict__ v1, const int* __restrict__ o1,
    const float* __restrict__ W2, const int* __restrict__ v2, const int* __restrict__ o2,
    const float* __restrict__ W3, const int* __restrict__ v3, const int* __restrict__ o3,
    float* __restrict__ out)
{
    const int table = threadIdx.x >> 6;
    const int lane  = threadIdx.x & 63;
    const int g     = lane >> 4;          // row group 0..3
    const int s     = lane & 15;          // float4 slot within row
    const int b0    = blockIdx.x * NB;

    const float* W; const int* vals; const int* offs;
    if      (table == 0) { W = W0; vals = v0; offs = o0; }
    else if (table == 1) { W = W1; vals = v1; offs = o1; }
    else if (table == 2) { W = W2; vals = v2; offs = o2; }
    else                 { W = W3; vals = v3; offs = o3; }

    // offsets for this block's bags: lane i (i<=NB) holds offs[b0+i]
    int off_reg = 0;
    if (lane <= NB) off_reg = offs[b0 + lane];

    // --- chunk pipeline ---
    int cb    = 0;                       // current bag (within block)
    int cbase = OFF(0);                  // absolute position of current chunk
    int cend  = OFF(1);
    int cn    = cend - cbase; cn = cn < 0 ? 0 : (cn > 64 ? 64 : cn);
    int v_cur = 0;
    if (lane < cn) v_cur = vals[cbase + lane];

    float4 acc0 = {0,0,0,0}, acc1 = {0,0,0,0}, acc2 = {0,0,0,0}, acc3 = {0,0,0,0};

    while (cb < NB) {
        // next chunk cursor (visits every bag at least once)
        int nb = cb, nbase = cbase + 64;
        if (nbase >= cend) { nb = cb + 1; nbase = (nb < NB) ? OFF(nb) : 0; }

        // issue 16 branch-free gathers for the current chunk
        const int srcmax = cn > 0 ? cn - 1 : 0;
        float4 t[16];
        #pragma unroll
        for (int k = 0; k < 16; ++k) {
            const int r   = 4 * k + g;
            const int src = r < srcmax ? r : srcmax;
            const int idx = __shfl(v_cur, src);
            t[k] = *(const float4*)(W + (size_t)idx * DIM + s * 4);
        }

        // issue next chunk's index load (overlaps with the gathers above)
        int nn = 0, nend = 0, v_nxt = 0;
        if (nb < NB) {
            nend = OFF(nb + 1);
            nn   = nend - nbase; nn = nn < 0 ? 0 : (nn > 64 ? 64 : nn);
            if (lane < nn) v_nxt = vals[nbase + lane];
        }

        // accumulate (compiler interleaves fine-grained vmcnt waits)
        #pragma unroll
        for (int k = 0; k < 16; ++k) {
            const float wk = (4 * k + g < cn) ? 1.0f : 0.0f;
            float4* a = (k & 3) == 0 ? &acc0 : (k & 3) == 1 ? &acc1
                       : (k & 3) == 2 ? &acc2 : &acc3;
            a->x = fmaf(t[k].x, wk, a->x);
            a->y = fmaf(t[k].y, wk, a->y);
            a->z = fmaf(t[k].z, wk, a->z);
            a->w = fmaf(t[k].w, wk, a->w);
        }

        // bag boundary: reduce + store, reset accumulators
        if (nb != cb) {
            float4 acc;
            acc.x = (acc0.x + acc1.x) + (acc2.x + acc3.x);
            acc.y = (acc0.y + acc1.y) + (acc2.y + acc3.y);
            acc.z = (acc0.z + acc1.z) + (acc2.z + acc3.z);
            acc.w = (acc0.w + acc1.w) + (acc2.w + acc3.w);
            acc.x += __shfl_xor(acc.x, 16); acc.y += __shfl_xor(acc.y, 16);
            acc.z += __shfl_xor(acc.z, 16); acc.w += __shfl_xor(acc.w, 16);
            acc.x += __shfl_xor(acc.x, 32); acc.y += __shfl_xor(acc.y, 32);
            acc.z += __shfl_xor(acc.z, 32); acc.w += __shfl_xor(acc.w, 32);

            const int len = cend - OFF(cb);
            const float inv = len > 0 ? 1.0f / (float)len : 0.0f;
            if (g == 0) {
                float4 r;
                r.x = acc.x * inv; r.y = acc.y * inv;
                r.z = acc.z * inv; r.w = acc.w * inv;
                *(float4*)(out + (size_t)(b0 + cb) * (4 * DIM) + table * DIM + s * 4) = r;
            }
            acc0 = acc1 = acc2 = acc3 = make_float4(0.f, 0.f, 0.f, 0.f);
        }

        cb = nb; cbase = nbase; cend = nend; cn = nn; v_cur = v_nxt;
    }
}

extern "C" void kernel_launch(void* const* d_in, const int* in_sizes, int n_in,
                              void* d_out, int out_size, void* d_ws, size_t ws_size,
                              hipStream_t stream) {
    const float* W0 = (const float*)d_in[0];
    const int*   v0 = (const int*)  d_in[1];
    const int*   o0 = (const int*)  d_in[2];
    const float* W1 = (const float*)d_in[3];
    const int*   v1 = (const int*)  d_in[4];
    const int*   o1 = (const int*)  d_in[5];
    const float* W2 = (const float*)d_in[6];
    const int*   v2 = (const int*)  d_in[7];
    const int*   o2 = (const int*)  d_in[8];
    const float* W3 = (const float*)d_in[9];
    const int*   v3 = (const int*)  d_in[10];
    const int*   o3 = (const int*)  d_in[11];
    float* out = (float*)d_out;

    ebc_kernel<<<NBAGS / NB, 256, 0, stream>>>(W0, v0, o0, W1, v1, o1,
                                               W2, v2, o2, W3, v3, o3, out);
}

// Round 5
// 77.006 us; speedup vs baseline: 1.1069x; 1.1069x over previous
//
#include <hip/hip_runtime.h>

// EmbeddingBagCollection: 4 tables, W[1M,64] fp32, mean-pool over jagged bags.
// block = NB bags, wave = table, lane = 16*g + s (g=row group, s=float4 slot).
// Chunk pipeline per wave: while chunk i's 16 branch-free float4 gathers (16KB)
// are in flight, chunk i+1's index load is also outstanding. NB=2 keeps grid at
// 4096 blocks (4x CU oversubscription) so bag-length imbalance is rebalanced by
// the scheduler -- R4's NB=8 (1024 blocks) starved TLP (occupancy 24%).

#define NBAGS 8192
#define DIM 64
#define NB 2                    // bags per block
#define OFF(i) __shfl(off_reg, (i))

__global__ __launch_bounds__(256) void ebc_kernel(
    const float* __restrict__ W0, const int* __restrict__ v0, const int* __restrict__ o0,
    const float* __restrict__ W1, const int* __restrict__ v1, const int* __restrict__ o1,
    const float* __restrict__ W2, const int* __restrict__ v2, const int* __restrict__ o2,
    const float* __restrict__ W3, const int* __restrict__ v3, const int* __restrict__ o3,
    float* __restrict__ out)
{
    const int table = threadIdx.x >> 6;
    const int lane  = threadIdx.x & 63;
    const int g     = lane >> 4;          // row group 0..3
    const int s     = lane & 15;          // float4 slot within row
    const int b0    = blockIdx.x * NB;

    const float* W; const int* vals; const int* offs;
    if      (table == 0) { W = W0; vals = v0; offs = o0; }
    else if (table == 1) { W = W1; vals = v1; offs = o1; }
    else if (table == 2) { W = W2; vals = v2; offs = o2; }
    else                 { W = W3; vals = v3; offs = o3; }

    // offsets for this block's bags: lane i (i<=NB) holds offs[b0+i]
    int off_reg = 0;
    if (lane <= NB) off_reg = offs[b0 + lane];

    // --- chunk pipeline ---
    int cb    = 0;                       // current bag (within block)
    int cbase = OFF(0);                  // absolute position of current chunk
    int cend  = OFF(1);
    int cn    = cend - cbase; cn = cn < 0 ? 0 : (cn > 64 ? 64 : cn);
    int v_cur = 0;
    if (lane < cn) v_cur = vals[cbase + lane];

    float4 acc0 = {0,0,0,0}, acc1 = {0,0,0,0}, acc2 = {0,0,0,0}, acc3 = {0,0,0,0};

    while (cb < NB) {
        // next chunk cursor (visits every bag at least once)
        int nb = cb, nbase = cbase + 64;
        if (nbase >= cend) { nb = cb + 1; nbase = (nb < NB) ? OFF(nb) : 0; }

        // issue 16 branch-free gathers for the current chunk
        const int srcmax = cn > 0 ? cn - 1 : 0;
        float4 t[16];
        #pragma unroll
        for (int k = 0; k < 16; ++k) {
            const int r   = 4 * k + g;
            const int src = r < srcmax ? r : srcmax;
            const int idx = __shfl(v_cur, src);
            t[k] = *(const float4*)(W + (size_t)idx * DIM + s * 4);
        }

        // issue next chunk's index load (overlaps with the gathers above)
        int nn = 0, nend = 0, v_nxt = 0;
        if (nb < NB) {
            nend = OFF(nb + 1);
            nn   = nend - nbase; nn = nn < 0 ? 0 : (nn > 64 ? 64 : nn);
            if (lane < nn) v_nxt = vals[nbase + lane];
        }

        // accumulate (compiler interleaves fine-grained vmcnt waits)
        #pragma unroll
        for (int k = 0; k < 16; ++k) {
            const float wk = (4 * k + g < cn) ? 1.0f : 0.0f;
            float4* a = (k & 3) == 0 ? &acc0 : (k & 3) == 1 ? &acc1
                       : (k & 3) == 2 ? &acc2 : &acc3;
            a->x = fmaf(t[k].x, wk, a->x);
            a->y = fmaf(t[k].y, wk, a->y);
            a->z = fmaf(t[k].z, wk, a->z);
            a->w = fmaf(t[k].w, wk, a->w);
        }

        // bag boundary: reduce + store, reset accumulators
        if (nb != cb) {
            float4 acc;
            acc.x = (acc0.x + acc1.x) + (acc2.x + acc3.x);
            acc.y = (acc0.y + acc1.y) + (acc2.y + acc3.y);
            acc.z = (acc0.z + acc1.z) + (acc2.z + acc3.z);
            acc.w = (acc0.w + acc1.w) + (acc2.w + acc3.w);
            acc.x += __shfl_xor(acc.x, 16); acc.y += __shfl_xor(acc.y, 16);
            acc.z += __shfl_xor(acc.z, 16); acc.w += __shfl_xor(acc.w, 16);
            acc.x += __shfl_xor(acc.x, 32); acc.y += __shfl_xor(acc.y, 32);
            acc.z += __shfl_xor(acc.z, 32); acc.w += __shfl_xor(acc.w, 32);

            const int len = cend - OFF(cb);
            const float inv = len > 0 ? 1.0f / (float)len : 0.0f;
            if (g == 0) {
                float4 r;
                r.x = acc.x * inv; r.y = acc.y * inv;
                r.z = acc.z * inv; r.w = acc.w * inv;
                *(float4*)(out + (size_t)(b0 + cb) * (4 * DIM) + table * DIM + s * 4) = r;
            }
            acc0 = acc1 = acc2 = acc3 = make_float4(0.f, 0.f, 0.f, 0.f);
        }

        cb = nb; cbase = nbase; cend = nend; cn = nn; v_cur = v_nxt;
    }
}

extern "C" void kernel_launch(void* const* d_in, const int* in_sizes, int n_in,
                              void* d_out, int out_size, void* d_ws, size_t ws_size,
                              hipStream_t stream) {
    const float* W0 = (const float*)d_in[0];
    const int*   v0 = (const int*)  d_in[1];
    const int*   o0 = (const int*)  d_in[2];
    const float* W1 = (const float*)d_in[3];
    const int*   v1 = (const int*)  d_in[4];
    const int*   o1 = (const int*)  d_in[5];
    const float* W2 = (const float*)d_in[6];
    const int*   v2 = (const int*)  d_in[7];
    const int*   o2 = (const int*)  d_in[8];
    const float* W3 = (const float*)d_in[9];
    const int*   v3 = (const int*)  d_in[10];
    const int*   o3 = (const int*)  d_in[11];
    float* out = (float*)d_out;

    ebc_kernel<<<NBAGS / NB, 256, 0, stream>>>(W0, v0, o0, W1, v1, o1,
                                               W2, v2, o2, W3, v3, o3, out);
}